// Round 6
// baseline (91.134 us; speedup 1.0000x reference)
//
#include <hip/hip_runtime.h>

#define HID 256
#define K27 27

typedef __attribute__((ext_vector_type(8))) short    bf16x8;
typedef __attribute__((ext_vector_type(4))) float    f32x4;
typedef __attribute__((ext_vector_type(4))) unsigned u32x4;

static __device__ __forceinline__ unsigned short f2bf(float f) {
    union { float f; unsigned u; } v; v.f = f;   // cold path only (staging)
    return (unsigned short)((v.u + 0x7FFFu + ((v.u >> 16) & 1u)) >> 16);
}
// (lo,hi) -> one u32 holding 2 bf16, single v_cvt_pk_bf16_f32
static __device__ __forceinline__ unsigned pack2bf(float lo, float hi) {
    unsigned r;
    asm("v_cvt_pk_bf16_f32 %0, %1, %2" : "=v"(r) : "v"(lo), "v"(hi));
    return r;
}
static __device__ __forceinline__ bf16x8 as_bf16x8(u32x4 u) {
    return __builtin_bit_cast(bf16x8, u);
}

// v5 = v4b with the occupancy fix: grid 2048 (=8 blocks/CU; LDS exactly 20KB
// -> 8 fit; VGPR 64 -> 8 waves/SIMD fit) so the CU holds 32 waves and the
// ds_read/MFMA/shfl dependency chains hide under TLP. Plus: int2 mapping
// loads, OR-fused bounds test (valid <=> ((u)y|(u)x) < 512).
__global__ __launch_bounds__(256, 4) void mapnet_v5(
    const float* __restrict__ pos,      // (P,3)
    const int*   __restrict__ mapping,  // (P,2)
    const float* __restrict__ feats,    // (3,512,512)
    const float* __restrict__ W1,       // (256,3)
    const float* __restrict__ b1,       // (256)
    const float* __restrict__ W2,       // (27,256)
    const float* __restrict__ b2,       // (27)
    float* __restrict__ out)            // (P)
{
    __shared__ float4  sW1[HID];        // {w0,w1,w2,b1}  (4 KB)
    __shared__ bf16x8  sB[16][64];      // [kc*2+nt][lane], fragment-order W2^T (16 KB)

    const int tid = threadIdx.x;
    for (int i = tid; i < HID; i += 256)
        sW1[i] = make_float4(W1[3*i], W1[3*i+1], W1[3*i+2], b1[i]);

    for (int e = tid; e < 1024; e += 256) {
        const int kcnt = e >> 6, l = e & 63;
        const int kc = kcnt >> 1, nt = kcnt & 1;
        const int gg = l >> 4, cc = l & 15;
        const int n = nt*16 + cc;
        u32x4 bb;
        #pragma unroll
        for (int i = 0; i < 4; ++i) {
            const int j0 = kc*32 + gg + 8*i;        // elem 2i -> j0, 2i+1 -> j0+4
            float f0 = 0.f, f1 = 0.f;
            if (n < K27) { f0 = W2[n*HID + j0]; f1 = W2[n*HID + j0 + 4]; }
            bb[i] = (unsigned)f2bf(f0) | ((unsigned)f2bf(f1) << 16);
        }
        sB[kcnt][l] = as_bf16x8(bb);
    }
    __syncthreads();

    const int lane = tid & 63, wid = tid >> 6;
    const int g = lane >> 4, col = lane & 15;

    const float b2A = b2[col];
    const float b2B = (col < K27 - 16) ? b2[16 + col] : 0.0f;
    const int kA = col;
    const int cA = kA/9, dyA = (kA%9)/3 - 1, dxA = (kA%9)%3 - 1;
    const int kB = min(16 + col, K27 - 1);          // clamped -> valid addr; acc1==0 there
    const int cB = kB/9, dyB = (kB%9)/3 - 1, dxB = (kB%9)%3 - 1;

    const float* fbaseA = feats + cA * (512*512);
    const float* fbaseB = feats + cB * (512*512);
    const int2*  map2   = (const int2*)mapping;

    const int w = blockIdx.x * 4 + wid;             // 0..8191

    for (int it = 0; it < 4; ++it) {
        const int tb0 = (w * 8 + it * 2) * 16;      // 8 tiles/wave, 2/iter
        const int tb1 = tb0 + 16;

        const float p00 = pos[3*(tb0+col)], p01 = pos[3*(tb0+col)+1], p02 = pos[3*(tb0+col)+2];
        const float p10 = pos[3*(tb1+col)], p11 = pos[3*(tb1+col)+1], p12 = pos[3*(tb1+col)+2];

        // ---- gathers issued BEFORE the MFMA loop (latency hides under h) ----
        float fvA[2][4], fvB[2][4];
        #pragma unroll
        for (int tt = 0; tt < 2; ++tt) {
            const int tb = tt ? tb1 : tb0;
            #pragma unroll
            for (int r = 0; r < 4; ++r) {
                const int2 mp = map2[tb + g*4 + r];
                const int my = mp.x, mx = mp.y;
                int y  = my + dyA, x  = mx + dxA;
                int yc = min(max(y,0),511), xc = min(max(x,0),511);
                float f = fbaseA[yc*512 + xc];
                fvA[tt][r] = (((unsigned)y | (unsigned)x) < 512u) ? f : 0.f;
                int y2 = my + dyB, x2 = mx + dxB;
                int yc2 = min(max(y2,0),511), xc2 = min(max(x2,0),511);
                float f2 = fbaseB[yc2*512 + xc2];
                fvB[tt][r] = (((unsigned)y2 | (unsigned)x2) < 512u) ? f2 : 0.f;
            }
        }

        f32x4 acc00 = {b2A,b2A,b2A,b2A}, acc01 = {b2B,b2B,b2B,b2B};
        f32x4 acc10 = {b2A,b2A,b2A,b2A}, acc11 = {b2B,b2B,b2B,b2B};

        #pragma unroll
        for (int kc = 0; kc < 8; ++kc) {
            u32x4 a0, a1;
            #pragma unroll
            for (int i = 0; i < 4; ++i) {
                const float4 wA = sW1[kc*32 + g + 8*i];
                const float4 wB = sW1[kc*32 + g + 8*i + 4];
                float x00 = fmaf(p00,wA.x,fmaf(p01,wA.y,fmaf(p02,wA.z,wA.w)));
                float x01 = fmaf(p00,wB.x,fmaf(p01,wB.y,fmaf(p02,wB.z,wB.w)));
                float x10 = fmaf(p10,wA.x,fmaf(p11,wA.y,fmaf(p12,wA.z,wA.w)));
                float x11 = fmaf(p10,wB.x,fmaf(p11,wB.y,fmaf(p12,wB.z,wB.w)));
                x00 = fmaxf(x00, 0.01f*x00); x01 = fmaxf(x01, 0.01f*x01);
                x10 = fmaxf(x10, 0.01f*x10); x11 = fmaxf(x11, 0.01f*x11);
                a0[i] = pack2bf(x00, x01);
                a1[i] = pack2bf(x10, x11);
            }
            const bf16x8 av0 = as_bf16x8(a0);
            const bf16x8 av1 = as_bf16x8(a1);
            const bf16x8 bv0 = sB[kc*2    ][lane];
            const bf16x8 bv1 = sB[kc*2 + 1][lane];
            acc00 = __builtin_amdgcn_mfma_f32_16x16x32_bf16(av0, bv0, acc00, 0,0,0);
            acc01 = __builtin_amdgcn_mfma_f32_16x16x32_bf16(av0, bv1, acc01, 0,0,0);
            acc10 = __builtin_amdgcn_mfma_f32_16x16x32_bf16(av1, bv0, acc10, 0,0,0);
            acc11 = __builtin_amdgcn_mfma_f32_16x16x32_bf16(av1, bv1, acc11, 0,0,0);
        }

        // ---- combine: C/D layout col=lane&15 (k27), row=g*4+r (pixel) ----
        #pragma unroll
        for (int tt = 0; tt < 2; ++tt) {
            const int tb = tt ? tb1 : tb0;
            const f32x4 aA = tt ? acc10 : acc00;
            const f32x4 aB = tt ? acc11 : acc01;
            #pragma unroll
            for (int r = 0; r < 4; ++r) {
                float s = aA[r] * fvA[tt][r] + aB[r] * fvB[tt][r];
                s += __shfl_xor(s, 1);
                s += __shfl_xor(s, 2);
                s += __shfl_xor(s, 4);
                s += __shfl_xor(s, 8);
                if (col == r) out[tb + g*4 + r] = s;
            }
        }
    }
}

extern "C" void kernel_launch(void* const* d_in, const int* in_sizes, int n_in,
                              void* d_out, int out_size, void* d_ws, size_t ws_size,
                              hipStream_t stream) {
    const float* pos     = (const float*)d_in[0];
    const int*   mapping = (const int*)d_in[1];
    const float* feats   = (const float*)d_in[2];
    // d_in[3] = depth, unused
    const float* W1      = (const float*)d_in[4];
    const float* b1      = (const float*)d_in[5];
    const float* W2      = (const float*)d_in[6];
    const float* b2      = (const float*)d_in[7];
    float* out = (float*)d_out;

    // P = 1024*1024: 65536 tiles; 2048 blocks x 4 waves x 8 tiles = 8 blocks/CU
    mapnet_v5<<<2048, 256, 0, stream>>>(pos, mapping, feats, W1, b1, W2, b2, out);
}

// Round 7
// 80.387 us; speedup vs baseline: 1.1337x; 1.1337x over previous
//
#include <hip/hip_runtime.h>

#define HID 256
#define K27 27

typedef __attribute__((ext_vector_type(8))) short    bf16x8;
typedef __attribute__((ext_vector_type(4))) float    f32x4;
typedef __attribute__((ext_vector_type(4))) unsigned u32x4;

static __device__ __forceinline__ unsigned short f2bf(float f) {
    union { float f; unsigned u; } v; v.f = f;   // cold path only (staging)
    return (unsigned short)((v.u + 0x7FFFu + ((v.u >> 16) & 1u)) >> 16);
}
// (lo,hi) -> one u32 holding 2 bf16, single v_cvt_pk_bf16_f32
static __device__ __forceinline__ unsigned pack2bf(float lo, float hi) {
    unsigned r;
    asm("v_cvt_pk_bf16_f32 %0, %1, %2" : "=v"(r) : "v"(lo), "v"(hi));
    return r;
}
static __device__ __forceinline__ bf16x8 as_bf16x8(u32x4 u) {
    return __builtin_bit_cast(bf16x8, u);
}
// fragment with only element 0 (low bf16 of word 0) populated
static __device__ __forceinline__ bf16x8 frag1(unsigned u) {
    u32x4 t = {u, 0u, 0u, 0u};
    return __builtin_bit_cast(bf16x8, t);
}
static __device__ __forceinline__ float lk(float x) {   // leaky_relu(0.01)
    return fmaxf(x, 0.01f * x);
}

// v6: BOTH layers on MFMA. Layer-1 uses the matched-slot trick: A and B
// fragments have only elem-0 per lane nonzero, so the contraction is exactly
// sum_g A(g,0)*B(g,0) = w0*p0+w1*p1+w2*p2+b1*1 (b1 in the g=3 slot). A (W1)
// comes from a 4KB LDS array via one ds_read_b32 per jt; B (pos) is built
// in-register. The L1 MFMA output layout (pixel=lane&15, j=16jt+4g+reg) IS
// the L2 A-fragment orientation, so leaky+cvt_pk feeds L2 directly; sB is
// staged with the matching j-map j = 32kc + 16(e>>2) + 4g + (e&3).
// This removes all 32 per-tile sW1 ds_read_b128 and the L1 FMA chains.
__global__ __launch_bounds__(256, 4) void mapnet_v6(
    const float* __restrict__ pos,      // (P,3)
    const int*   __restrict__ mapping,  // (P,2)
    const float* __restrict__ feats,    // (3,512,512)
    const float* __restrict__ W1,       // (256,3)
    const float* __restrict__ b1,       // (256)
    const float* __restrict__ W2,       // (27,256)
    const float* __restrict__ b2,       // (27)
    float* __restrict__ out)            // (P)
{
    __shared__ unsigned sW1f[16][64];   // [jt][lane]: pack2bf(W1val, 0)  (4 KB)
    __shared__ bf16x8   sB[16][64];     // [kc*2+nt][lane]: L2 B-frags    (16 KB)

    const int tid = threadIdx.x;

    // ---- stage L1 A-fragments: lane (g,cc) of tile jt needs W1[16jt+cc][g] (g=3 -> b1)
    for (int e = tid; e < 1024; e += 256) {
        const int jt = e >> 6, l = e & 63;
        const int gg = l >> 4, cc = l & 15;
        const int j = jt * 16 + cc;
        const float val = (gg < 3) ? W1[3 * j + gg] : b1[j];
        sW1f[jt][l] = pack2bf(val, 0.0f);
    }
    // ---- stage L2 B-fragments with j-map matching the L1 output layout
    for (int e = tid; e < 1024; e += 256) {
        const int kcnt = e >> 6, l = e & 63;
        const int kc = kcnt >> 1, nt = kcnt & 1;
        const int gg = l >> 4, cc = l & 15;
        const int n = nt * 16 + cc;
        const int jbase = kc * 32 + 4 * gg;
        u32x4 bb;
        #pragma unroll
        for (int i = 0; i < 4; ++i) {
            const int jlo = jbase + 16 * (i >> 1) + 2 * (i & 1);
            float f0 = 0.f, f1 = 0.f;
            if (n < K27) { f0 = W2[n * HID + jlo]; f1 = W2[n * HID + jlo + 1]; }
            bb[i] = (unsigned)f2bf(f0) | ((unsigned)f2bf(f1) << 16);
        }
        sB[kcnt][l] = as_bf16x8(bb);
    }
    __syncthreads();

    const int lane = tid & 63, wid = tid >> 6;
    const int g = lane >> 4, col = lane & 15;

    const float b2A = b2[col];
    const float b2B = (col < K27 - 16) ? b2[16 + col] : 0.0f;
    const int kA = col;
    const int cA = kA/9, dyA = (kA%9)/3 - 1, dxA = (kA%9)%3 - 1;
    const int kB = min(16 + col, K27 - 1);          // clamped -> valid addr; acc1==0 there
    const int cB = kB/9, dyB = (kB%9)/3 - 1, dxB = (kB%9)%3 - 1;

    const float* fbaseA = feats + cA * (512*512);
    const float* fbaseB = feats + cB * (512*512);
    const int2*  map2   = (const int2*)mapping;

    const int w = blockIdx.x * 4 + wid;             // 0..8191

    for (int it = 0; it < 4; ++it) {
        const int tb0 = (w * 8 + it * 2) * 16;      // 8 tiles/wave, 2/iter
        const int tb1 = tb0 + 16;

        // pos for this lane's pixel (row = col) of each tile
        const float q00 = pos[3*(tb0+col)], q01 = pos[3*(tb0+col)+1], q02 = pos[3*(tb0+col)+2];
        const float q10 = pos[3*(tb1+col)], q11 = pos[3*(tb1+col)+1], q12 = pos[3*(tb1+col)+2];
        // L1 B-fragment: elem0 = pos component g (g=3 -> 1.0 for the bias slot)
        const float v0 = (g == 0) ? q00 : (g == 1) ? q01 : (g == 2) ? q02 : 1.0f;
        const float v1 = (g == 0) ? q10 : (g == 1) ? q11 : (g == 2) ? q12 : 1.0f;
        const bf16x8 pB0 = frag1(pack2bf(v0, 0.0f));
        const bf16x8 pB1 = frag1(pack2bf(v1, 0.0f));

        // ---- gathers issued early (latency hides under the MFMA pipeline) ----
        float fvA[2][4], fvB[2][4];
        #pragma unroll
        for (int tt = 0; tt < 2; ++tt) {
            const int tb = tt ? tb1 : tb0;
            #pragma unroll
            for (int r = 0; r < 4; ++r) {
                const int2 mp = map2[tb + g*4 + r];
                const int my = mp.x, mx = mp.y;
                int y  = my + dyA, x  = mx + dxA;
                int yc = min(max(y,0),511), xc = min(max(x,0),511);
                float f = fbaseA[yc*512 + xc];
                fvA[tt][r] = (((unsigned)y | (unsigned)x) < 512u) ? f : 0.f;
                int y2 = my + dyB, x2 = mx + dxB;
                int yc2 = min(max(y2,0),511), xc2 = min(max(x2,0),511);
                float f2 = fbaseB[yc2*512 + xc2];
                fvB[tt][r] = (((unsigned)y2 | (unsigned)x2) < 512u) ? f2 : 0.f;
            }
        }

        f32x4 acc00 = {b2A,b2A,b2A,b2A}, acc01 = {b2B,b2B,b2B,b2B};
        f32x4 acc10 = {b2A,b2A,b2A,b2A}, acc11 = {b2B,b2B,b2B,b2B};
        const f32x4 zero = {0.f, 0.f, 0.f, 0.f};

        #pragma unroll
        for (int kc = 0; kc < 8; ++kc) {
            const bf16x8 wA0 = frag1(sW1f[2*kc    ][lane]);
            const bf16x8 wA1 = frag1(sW1f[2*kc + 1][lane]);

            // L1: h[j][px] for jt = 2kc, 2kc+1; lane holds j=16jt+4g+r, px=col
            const f32x4 c00 = __builtin_amdgcn_mfma_f32_16x16x32_bf16(wA0, pB0, zero, 0,0,0);
            const f32x4 c01 = __builtin_amdgcn_mfma_f32_16x16x32_bf16(wA1, pB0, zero, 0,0,0);
            const f32x4 c10 = __builtin_amdgcn_mfma_f32_16x16x32_bf16(wA0, pB1, zero, 0,0,0);
            const f32x4 c11 = __builtin_amdgcn_mfma_f32_16x16x32_bf16(wA1, pB1, zero, 0,0,0);

            // leaky + pack -> L2 A-fragment (elem e: e<4 -> c_jt0[e], e>=4 -> c_jt1[e-4])
            u32x4 a0, a1;
            a0[0] = pack2bf(lk(c00[0]), lk(c00[1]));
            a0[1] = pack2bf(lk(c00[2]), lk(c00[3]));
            a0[2] = pack2bf(lk(c01[0]), lk(c01[1]));
            a0[3] = pack2bf(lk(c01[2]), lk(c01[3]));
            a1[0] = pack2bf(lk(c10[0]), lk(c10[1]));
            a1[1] = pack2bf(lk(c10[2]), lk(c10[3]));
            a1[2] = pack2bf(lk(c11[0]), lk(c11[1]));
            a1[3] = pack2bf(lk(c11[2]), lk(c11[3]));
            const bf16x8 av0 = as_bf16x8(a0);
            const bf16x8 av1 = as_bf16x8(a1);

            const bf16x8 bv0 = sB[kc*2    ][lane];
            const bf16x8 bv1 = sB[kc*2 + 1][lane];
            acc00 = __builtin_amdgcn_mfma_f32_16x16x32_bf16(av0, bv0, acc00, 0,0,0);
            acc01 = __builtin_amdgcn_mfma_f32_16x16x32_bf16(av0, bv1, acc01, 0,0,0);
            acc10 = __builtin_amdgcn_mfma_f32_16x16x32_bf16(av1, bv0, acc10, 0,0,0);
            acc11 = __builtin_amdgcn_mfma_f32_16x16x32_bf16(av1, bv1, acc11, 0,0,0);
        }

        // ---- combine: C/D layout col=lane&15 (k27), row=g*4+r (pixel) ----
        #pragma unroll
        for (int tt = 0; tt < 2; ++tt) {
            const int tb = tt ? tb1 : tb0;
            const f32x4 aA = tt ? acc10 : acc00;
            const f32x4 aB = tt ? acc11 : acc01;
            #pragma unroll
            for (int r = 0; r < 4; ++r) {
                float s = aA[r] * fvA[tt][r] + aB[r] * fvB[tt][r];
                s += __shfl_xor(s, 1);
                s += __shfl_xor(s, 2);
                s += __shfl_xor(s, 4);
                s += __shfl_xor(s, 8);
                if (col == r) out[tb + g*4 + r] = s;
            }
        }
    }
}

extern "C" void kernel_launch(void* const* d_in, const int* in_sizes, int n_in,
                              void* d_out, int out_size, void* d_ws, size_t ws_size,
                              hipStream_t stream) {
    const float* pos     = (const float*)d_in[0];
    const int*   mapping = (const int*)d_in[1];
    const float* feats   = (const float*)d_in[2];
    // d_in[3] = depth, unused
    const float* W1      = (const float*)d_in[4];
    const float* b1      = (const float*)d_in[5];
    const float* W2      = (const float*)d_in[6];
    const float* b2      = (const float*)d_in[7];
    float* out = (float*)d_out;

    // P = 1024*1024: 65536 tiles; 2048 blocks x 4 waves x 8 tiles
    mapnet_v6<<<2048, 256, 0, stream>>>(pos, mapping, feats, W1, b1, W2, b2, out);
}